// Round 1
// baseline (284.896 us; speedup 1.0000x reference)
//
#include <hip/hip_runtime.h>

// B=1048576, A=3, N=8, NUM_CLASSES=3, LAMBDA_COORD=5
#define B_SIZE 1048576
#define NBLK   4096           // 256 threads/block, 64 batches/wave
#define NPART  (NBLK * 4)     // one double partial per wave

__device__ __forceinline__ float frcp(float x) { return __builtin_amdgcn_rcpf(x); }

__global__ __launch_bounds__(256, 5) void yolo_loss_kernel(
    const float* __restrict__ pred,       // [B,3,8]  row = 24 floats
    const float* __restrict__ gt_boxes,   // [B,8,4]  row = 32 floats
    const int*   __restrict__ gt_classes, // [B,8]    row = 8 ints
    double* __restrict__ part) {          // [NPART] per-wave partials (no atomics)
    // ONE time-multiplexed per-wave LDS buffer: 64 rows x 8 float4 slots = 8 KB.
    // 4 waves x 8 KB = 32768 B/block exactly -> 5 blocks/CU (was 2 at 59.9 KB).
    // XOR swizzle (slot ^ (row&7)) keeps 16-B alignment (b128 ops) AND breaks the
    // power-of-2 128-B row stride: reads/writes are <=2-way bank aliased (free).
    __shared__ float4 sBuf[4][64][8];

    const int tid  = threadIdx.x;
    const int wave = tid >> 6;
    const int lane = tid & 63;
    const int wb   = blockIdx.x * 256 + wave * 64;   // wave's batch base

    // ---- issue ALL global loads up front, fully coalesced (1 KB/instr) ----
    const float4* pA = reinterpret_cast<const float4*>(pred     + (size_t)wb * 24);
    const float4* gA = reinterpret_cast<const float4*>(gt_boxes + (size_t)wb * 32);
    float4 vp[6], vg[8];
    #pragma unroll
    for (int k = 0; k < 6; ++k) vp[k] = pA[k * 64 + lane];
    #pragma unroll
    for (int k = 0; k < 8; ++k) vg[k] = gA[k * 64 + lane];
    // classes: tiny (32 B/row); direct per-batch loads, 2 instructions
    const int4* cme = reinterpret_cast<const int4*>(gt_classes + (size_t)(wb + lane) * 8);
    const int4 c0 = cme[0], c1 = cme[1];

    float4 (*buf)[8] = sBuf[wave];

    // ---- pred transpose through LDS (6 b128 writes + 6 b128 reads) ----
    #pragma unroll
    for (int k = 0; k < 6; ++k) {
        const unsigned f  = k * 64 + lane;          // float4 idx in 64x6 pred slab
        const unsigned bl = f / 6u, of = f % 6u;    // magic-mul, constant divisor
        buf[bl][of ^ (bl & 7u)] = vp[k];
    }
    float pr[24];
    #pragma unroll
    for (int s = 0; s < 6; ++s) {
        const float4 t = buf[lane][s ^ (lane & 7)];
        pr[s*4+0] = t.x; pr[s*4+1] = t.y; pr[s*4+2] = t.z; pr[s*4+3] = t.w;
    }

    // ---- gt transpose through the SAME buffer (8 writes + 8 reads) ----
    // WAR-safe: buffer is wave-private, DS unit processes a wave's ops in issue
    // order, and the compiler cannot disprove aliasing so it preserves order.
    #pragma unroll
    for (int k = 0; k < 8; ++k) {
        const unsigned f  = k * 64 + lane;          // float4 idx in 64x8 gt slab
        const unsigned bl = f >> 3, of = f & 7;
        buf[bl][of ^ (bl & 7u)] = vg[k];
    }
    float gb[32];
    #pragma unroll
    for (int s = 0; s < 8; ++s) {
        const float4 t = buf[lane][s ^ (lane & 7)];
        gb[s*4+0] = t.x; gb[s*4+1] = t.y; gb[s*4+2] = t.z; gb[s*4+3] = t.w;
    }
    const int gc[8] = {c0.x, c0.y, c0.z, c0.w, c1.x, c1.y, c1.z, c1.w};

    // ---- per-anchor loss math (R2-validated, unchanged) ----
    float total = 0.0f;
    #pragma unroll
    for (int a = 0; a < 3; ++a) {
        const float* p = pr + a * 8;
        const float px = frcp(1.0f + __expf(-p[0]));
        const float py = frcp(1.0f + __expf(-p[1]));
        const float pw = p[2];
        const float ph = p[3];
        const float z  = p[4];
        const float px1 = px - pw * 0.5f, px2 = px + pw * 0.5f;
        const float py1 = py - ph * 0.5f, py2 = py + ph * 0.5f;
        const float pa_eps = (px2 - px1) * (py2 - py1) + 1e-6f;

        float best_iou = -3.4e38f;
        int best_idx = 0;
        #pragma unroll
        for (int n = 0; n < 8; ++n) {
            const float gx = gb[n*4+0], gy = gb[n*4+1];
            const float gw = gb[n*4+2], gh = gb[n*4+3];
            const float hw = gw * 0.5f, hh = gh * 0.5f;
            const float iw = fmaxf(fminf(px2, gx + hw) - fmaxf(px1, gx - hw), 0.0f);
            const float ih = fmaxf(fminf(py2, gy + hh) - fmaxf(py1, gy - hh), 0.0f);
            const float inter = iw * ih;
            const float iou = inter * frcp((pa_eps + gw * gh) - inter);
            const bool upd = iou > best_iou;       // strict > == first-max (argmax)
            best_iou = upd ? iou : best_iou;
            best_idx = upd ? n : best_idx;
        }
        const bool matched = best_iou > 0.5f;

        float mbx = gb[0], mby = gb[1], mbw = gb[2], mbh = gb[3];
        int mcls = gc[0];
        #pragma unroll
        for (int n = 1; n < 8; ++n) {
            const bool s = (best_idx == n);
            mbx = s ? gb[n*4+0] : mbx;
            mby = s ? gb[n*4+1] : mby;
            mbw = s ? gb[n*4+2] : mbw;
            mbh = s ? gb[n*4+3] : mbh;
            mcls = s ? gc[n] : mcls;
        }

        // conf loss via shared softplus (clamped):
        const float az = fabsf(z);
        const float c  = __logf(1.0f + __expf(-az));
        const float sp_pos = fmaxf(z, 0.0f) + c;
        const float sp_neg = fmaxf(-z, 0.0f) + c;
        total += fminf(matched ? sp_neg : sp_pos, 100.0f);

        if (matched) {
            const float dx = px - mbx, dy = py - mby;
            const float dw = pw - mbw, dh = ph - mbh;
            total += 5.0f * (dx*dx + dy*dy + dw*dw + dh*dh);
            const float l0 = p[5], l1 = p[6], l2 = p[7];
            const float m = fmaxf(l0, fmaxf(l1, l2));
            const float lse = m + __logf(__expf(l0-m) + __expf(l1-m) + __expf(l2-m));
            const float sel = (mcls == 0) ? l0 : ((mcls == 1) ? l1 : l2);
            total += lse - sel;
        }
    }

    // ---- wave(64) shuffle reduce -> per-WAVE partial store (no LDS, no atomics;
    //      keeps block LDS at exactly 32 KB so 5 blocks/CU fit) ----
    #pragma unroll
    for (int off = 32; off > 0; off >>= 1)
        total += __shfl_down(total, off, 64);
    if (lane == 0)
        part[(size_t)blockIdx.x * 4 + wave] = (double)total;
}

__global__ __launch_bounds__(256) void yolo_reduce_kernel(
    const double* __restrict__ part, float* __restrict__ out) {
    double s = 0.0;
    #pragma unroll
    for (int k = 0; k < NPART / 256; ++k)
        s += part[threadIdx.x + k * 256];      // coalesced
    #pragma unroll
    for (int off = 32; off > 0; off >>= 1)
        s += __shfl_down(s, off, 64);
    __shared__ double r[4];
    const int lane = threadIdx.x & 63;
    const int wave = threadIdx.x >> 6;
    if (lane == 0) r[wave] = s;
    __syncthreads();
    if (threadIdx.x == 0)
        out[0] = (float)((r[0] + r[1] + r[2] + r[3]) / (double)B_SIZE);
}

extern "C" void kernel_launch(void* const* d_in, const int* in_sizes, int n_in,
                              void* d_out, int out_size, void* d_ws, size_t ws_size,
                              hipStream_t stream) {
    const float* pred       = (const float*)d_in[0];
    const float* gt_boxes   = (const float*)d_in[1];
    const int*   gt_classes = (const int*)d_in[2];
    float* out   = (float*)d_out;
    double* part = (double*)d_ws;   // 16384 doubles = 128 KB scratch; every slot
                                    // written each launch (poison-safe)

    yolo_loss_kernel<<<NBLK, 256, 0, stream>>>(pred, gt_boxes, gt_classes, part);
    yolo_reduce_kernel<<<1, 256, 0, stream>>>(part, out);
}

// Round 2
// 280.165 us; speedup vs baseline: 1.0169x; 1.0169x over previous
//
#include <hip/hip_runtime.h>

// B=1048576, A=3, N=8, NUM_CLASSES=3, LAMBDA_COORD=5
#define B_SIZE 1048576
#define NBLK   4096           // 256 threads/block, 64 batches/wave
#define NPART  (NBLK * 4)     // one double partial per wave

__device__ __forceinline__ float frcp(float x) { return __builtin_amdgcn_rcpf(x); }

// NOTE: plain __launch_bounds__(256) — R1 showed (256,5) squeezes VGPR to 48 and
// spills 53 MB of scratch (WRITE_SIZE 128KB->53MB), flattening the occupancy win.
// Natural allocation for this math is ~88 VGPR (R0), which already permits
// 5 waves/SIMD (88*5=440<=512); LDS 32KB/block -> exactly 5 blocks/CU.
__global__ __launch_bounds__(256) void yolo_loss_kernel(
    const float* __restrict__ pred,       // [B,3,8]  row = 24 floats
    const float* __restrict__ gt_boxes,   // [B,8,4]  row = 32 floats
    const int*   __restrict__ gt_classes, // [B,8]    row = 8 ints
    double* __restrict__ part) {          // [NPART] per-wave partials (no atomics)
    // ONE time-multiplexed per-wave LDS buffer: 64 rows x 8 float4 slots = 8 KB.
    // 4 waves x 8 KB = 32768 B/block exactly -> 5 blocks/CU.
    // XOR swizzle (slot ^ (row&7)) keeps 16-B alignment (b128 ops) AND breaks the
    // power-of-2 128-B row stride on the read side (clean 8-slot permutation).
    __shared__ float4 sBuf[4][64][8];

    const int tid  = threadIdx.x;
    const int wave = tid >> 6;
    const int lane = tid & 63;
    const int wb   = blockIdx.x * 256 + wave * 64;   // wave's batch base

    // ---- issue ALL global loads up front, fully coalesced (1 KB/instr) ----
    const float4* pA = reinterpret_cast<const float4*>(pred     + (size_t)wb * 24);
    const float4* gA = reinterpret_cast<const float4*>(gt_boxes + (size_t)wb * 32);
    float4 vp[6], vg[8];
    #pragma unroll
    for (int k = 0; k < 6; ++k) vp[k] = pA[k * 64 + lane];
    #pragma unroll
    for (int k = 0; k < 8; ++k) vg[k] = gA[k * 64 + lane];
    // classes: tiny (32 B/row); direct per-batch loads, 2 instructions
    const int4* cme = reinterpret_cast<const int4*>(gt_classes + (size_t)(wb + lane) * 8);
    const int4 c0 = cme[0], c1 = cme[1];

    float4 (*buf)[8] = sBuf[wave];

    // ---- pred transpose through LDS (6 b128 writes + 6 b128 reads) ----
    #pragma unroll
    for (int k = 0; k < 6; ++k) {
        const unsigned f  = k * 64 + lane;          // float4 idx in 64x6 pred slab
        const unsigned bl = f / 6u, of = f % 6u;    // magic-mul, constant divisor
        buf[bl][of ^ (bl & 7u)] = vp[k];
    }
    float pr[24];
    #pragma unroll
    for (int s = 0; s < 6; ++s) {
        const float4 t = buf[lane][s ^ (lane & 7)];
        pr[s*4+0] = t.x; pr[s*4+1] = t.y; pr[s*4+2] = t.z; pr[s*4+3] = t.w;
    }

    // ---- gt transpose through the SAME buffer (8 writes + 8 reads) ----
    // WAR-safe: buffer is wave-private, DS unit processes a wave's ops in issue
    // order, and the compiler cannot disprove aliasing so it preserves order.
    #pragma unroll
    for (int k = 0; k < 8; ++k) {
        const unsigned f  = k * 64 + lane;          // float4 idx in 64x8 gt slab
        const unsigned bl = f >> 3, of = f & 7;
        buf[bl][of ^ (bl & 7u)] = vg[k];
    }
    float gb[32];
    #pragma unroll
    for (int s = 0; s < 8; ++s) {
        const float4 t = buf[lane][s ^ (lane & 7)];
        gb[s*4+0] = t.x; gb[s*4+1] = t.y; gb[s*4+2] = t.z; gb[s*4+3] = t.w;
    }
    const int gc[8] = {c0.x, c0.y, c0.z, c0.w, c1.x, c1.y, c1.z, c1.w};

    // ---- per-anchor loss math (R2-validated, unchanged) ----
    float total = 0.0f;
    #pragma unroll
    for (int a = 0; a < 3; ++a) {
        const float* p = pr + a * 8;
        const float px = frcp(1.0f + __expf(-p[0]));
        const float py = frcp(1.0f + __expf(-p[1]));
        const float pw = p[2];
        const float ph = p[3];
        const float z  = p[4];
        const float px1 = px - pw * 0.5f, px2 = px + pw * 0.5f;
        const float py1 = py - ph * 0.5f, py2 = py + ph * 0.5f;
        const float pa_eps = (px2 - px1) * (py2 - py1) + 1e-6f;

        float best_iou = -3.4e38f;
        int best_idx = 0;
        #pragma unroll
        for (int n = 0; n < 8; ++n) {
            const float gx = gb[n*4+0], gy = gb[n*4+1];
            const float gw = gb[n*4+2], gh = gb[n*4+3];
            const float hw = gw * 0.5f, hh = gh * 0.5f;
            const float iw = fmaxf(fminf(px2, gx + hw) - fmaxf(px1, gx - hw), 0.0f);
            const float ih = fmaxf(fminf(py2, gy + hh) - fmaxf(py1, gy - hh), 0.0f);
            const float inter = iw * ih;
            const float iou = inter * frcp((pa_eps + gw * gh) - inter);
            const bool upd = iou > best_iou;       // strict > == first-max (argmax)
            best_iou = upd ? iou : best_iou;
            best_idx = upd ? n : best_idx;
        }
        const bool matched = best_iou > 0.5f;

        float mbx = gb[0], mby = gb[1], mbw = gb[2], mbh = gb[3];
        int mcls = gc[0];
        #pragma unroll
        for (int n = 1; n < 8; ++n) {
            const bool s = (best_idx == n);
            mbx = s ? gb[n*4+0] : mbx;
            mby = s ? gb[n*4+1] : mby;
            mbw = s ? gb[n*4+2] : mbw;
            mbh = s ? gb[n*4+3] : mbh;
            mcls = s ? gc[n] : mcls;
        }

        // conf loss via shared softplus (clamped):
        const float az = fabsf(z);
        const float c  = __logf(1.0f + __expf(-az));
        const float sp_pos = fmaxf(z, 0.0f) + c;
        const float sp_neg = fmaxf(-z, 0.0f) + c;
        total += fminf(matched ? sp_neg : sp_pos, 100.0f);

        if (matched) {
            const float dx = px - mbx, dy = py - mby;
            const float dw = pw - mbw, dh = ph - mbh;
            total += 5.0f * (dx*dx + dy*dy + dw*dw + dh*dh);
            const float l0 = p[5], l1 = p[6], l2 = p[7];
            const float m = fmaxf(l0, fmaxf(l1, l2));
            const float lse = m + __logf(__expf(l0-m) + __expf(l1-m) + __expf(l2-m));
            const float sel = (mcls == 0) ? l0 : ((mcls == 1) ? l1 : l2);
            total += lse - sel;
        }
    }

    // ---- wave(64) shuffle reduce -> per-WAVE partial store (no LDS, no atomics;
    //      keeps block LDS at exactly 32 KB so 5 blocks/CU fit) ----
    #pragma unroll
    for (int off = 32; off > 0; off >>= 1)
        total += __shfl_down(total, off, 64);
    if (lane == 0)
        part[(size_t)blockIdx.x * 4 + wave] = (double)total;
}

__global__ __launch_bounds__(256) void yolo_reduce_kernel(
    const double* __restrict__ part, float* __restrict__ out) {
    double s = 0.0;
    #pragma unroll
    for (int k = 0; k < NPART / 256; ++k)
        s += part[threadIdx.x + k * 256];      // coalesced
    #pragma unroll
    for (int off = 32; off > 0; off >>= 1)
        s += __shfl_down(s, off, 64);
    __shared__ double r[4];
    const int lane = threadIdx.x & 63;
    const int wave = threadIdx.x >> 6;
    if (lane == 0) r[wave] = s;
    __syncthreads();
    if (threadIdx.x == 0)
        out[0] = (float)((r[0] + r[1] + r[2] + r[3]) / (double)B_SIZE);
}

extern "C" void kernel_launch(void* const* d_in, const int* in_sizes, int n_in,
                              void* d_out, int out_size, void* d_ws, size_t ws_size,
                              hipStream_t stream) {
    const float* pred       = (const float*)d_in[0];
    const float* gt_boxes   = (const float*)d_in[1];
    const int*   gt_classes = (const int*)d_in[2];
    float* out   = (float*)d_out;
    double* part = (double*)d_ws;   // 16384 doubles = 128 KB scratch; every slot
                                    // written each launch (poison-safe)

    yolo_loss_kernel<<<NBLK, 256, 0, stream>>>(pred, gt_boxes, gt_classes, part);
    yolo_reduce_kernel<<<1, 256, 0, stream>>>(part, out);
}